// Round 1
// baseline (71.633 us; speedup 1.0000x reference)
//
#include <hip/hip_runtime.h>
#include <math.h>

#define N_PRED 12
#define B      256
#define N_NEG  128
#define D      512
#define LOG2E  1.4426950408889634f
#define LN2    0.6931471805599453f

__device__ __forceinline__ float wave_reduce_sum(float v) {
#pragma unroll
    for (int off = 32; off > 0; off >>= 1)
        v += __shfl_xor(v, off, 64);
    return v;
}

// One block per (t,b). 4 waves; each wave handles negs n = wave, wave+4, ...
__global__ __launch_bounds__(256) void fk_kernel(
    const float* __restrict__ lp,        // (13,256,512)
    const float* __restrict__ ps,        // (12,256,512)
    const int*   __restrict__ time_idx,  // (12,256,128)
    const int*   __restrict__ batch_idx, // (12,256,128)
    float* __restrict__ per_step,        // (12*256)
    float* __restrict__ flags)           // (12*256)
{
    const int tb   = blockIdx.x;   // 0..3071
    const int t    = tb >> 8;
    const int b    = tb & (B - 1);
    const int tid  = threadIdx.x;
    const int wave = tid >> 6;
    const int lane = tid & 63;

    // pred row = lp[t+1, b, :], pre-scaled by log2(e) so exp(p*x) = exp2(pl*x)
    const float4* pred4 = (const float4*)(lp + ((size_t)(t + 1) * B + b) * D);
    float4 p0 = pred4[lane];
    float4 p1 = pred4[lane + 64];
    p0.x *= LOG2E; p0.y *= LOG2E; p0.z *= LOG2E; p0.w *= LOG2E;
    p1.x *= LOG2E; p1.y *= LOG2E; p1.z *= LOG2E; p1.w *= LOG2E;

    // fk_pos (computed redundantly by every wave — cheap, avoids a barrier)
    const float4* pos4 = (const float4*)(ps + ((size_t)t * B + b) * D);
    {
        // nothing
    }
    float4 x0 = pos4[lane];
    float4 x1 = pos4[lane + 64];
    float s;
    {
        float e0 = __builtin_amdgcn_exp2f(p0.x * x0.x);
        float e1 = __builtin_amdgcn_exp2f(p0.y * x0.y);
        float e2 = __builtin_amdgcn_exp2f(p0.z * x0.z);
        float e3 = __builtin_amdgcn_exp2f(p0.w * x0.w);
        float e4 = __builtin_amdgcn_exp2f(p1.x * x1.x);
        float e5 = __builtin_amdgcn_exp2f(p1.y * x1.y);
        float e6 = __builtin_amdgcn_exp2f(p1.z * x1.z);
        float e7 = __builtin_amdgcn_exp2f(p1.w * x1.w);
        s = ((e0 + e1) + (e2 + e3)) + ((e4 + e5) + (e6 + e7));
    }
    const float fk_pos = wave_reduce_sum(s);

    float negsum = 0.0f;
    int   all_ok = 1;
    const int idx_base = (t * B + b) * N_NEG;

#pragma unroll 2
    for (int n = wave; n < N_NEG; n += 4) {
        const int ti = time_idx[idx_base + n];
        const int bi = batch_idx[idx_base + n];
        // bank[ti, bi, :] : ti==0 -> lp[0, bi], else ps[ti-1, bi]
        const float* row = (ti == 0) ? (lp + (size_t)bi * D)
                                     : (ps + ((size_t)(ti - 1) * B + bi) * D);
        const float4* row4 = (const float4*)row;
        float4 y0 = row4[lane];
        float4 y1 = row4[lane + 64];
        float e0 = __builtin_amdgcn_exp2f(p0.x * y0.x);
        float e1 = __builtin_amdgcn_exp2f(p0.y * y0.y);
        float e2 = __builtin_amdgcn_exp2f(p0.z * y0.z);
        float e3 = __builtin_amdgcn_exp2f(p0.w * y0.w);
        float e4 = __builtin_amdgcn_exp2f(p1.x * y1.x);
        float e5 = __builtin_amdgcn_exp2f(p1.y * y1.y);
        float e6 = __builtin_amdgcn_exp2f(p1.z * y1.z);
        float e7 = __builtin_amdgcn_exp2f(p1.w * y1.w);
        float sn = ((e0 + e1) + (e2 + e3)) + ((e4 + e5) + (e6 + e7));
        float fk = wave_reduce_sum(sn);
        negsum += fk;
        all_ok &= (fk_pos > fk) ? 1 : 0;
    }

    __shared__ float s_sum[4];
    __shared__ int   s_ok[4];
    if (lane == 0) { s_sum[wave] = negsum; s_ok[wave] = all_ok; }
    __syncthreads();
    if (tid == 0) {
        float total_neg = (s_sum[0] + s_sum[1]) + (s_sum[2] + s_sum[3]);
        int ok = s_ok[0] & s_ok[1] & s_ok[2] & s_ok[3];
        float total = fk_pos + total_neg;
        // log(fk_pos / total) = (log2(fk_pos) - log2(total)) * ln2
        float lg = (__builtin_amdgcn_logf(fk_pos) - __builtin_amdgcn_logf(total)) * LN2;
        per_step[tb] = lg;
        flags[tb]    = (float)ok;
    }
}

// Block 0: loss; blocks 1..12: correct_predictions[t]
__global__ __launch_bounds__(256) void reduce_kernel(
    const float* __restrict__ per_step,
    const float* __restrict__ flags,
    float* __restrict__ out)
{
    const int tid = threadIdx.x;
    const int j   = blockIdx.x;
    __shared__ float sh[4];

    float s = 0.0f;
    if (j == 0) {
#pragma unroll
        for (int t = 0; t < N_PRED; ++t) s += per_step[t * B + tid];
    } else {
        s = flags[(j - 1) * B + tid];
    }
    s = wave_reduce_sum(s);
    if ((tid & 63) == 0) sh[tid >> 6] = s;
    __syncthreads();
    if (tid == 0) {
        float tot = (sh[0] + sh[1]) + (sh[2] + sh[3]);
        if (j == 0)
            out[0] = tot * (1.0f / ((float)(N_NEG + 1) * N_PRED * B));
        else
            out[j] = tot;
    }
}

extern "C" void kernel_launch(void* const* d_in, const int* in_sizes, int n_in,
                              void* d_out, int out_size, void* d_ws, size_t ws_size,
                              hipStream_t stream) {
    const float* lp        = (const float*)d_in[0];
    const float* ps        = (const float*)d_in[1];
    const int*   time_idx  = (const int*)d_in[2];
    const int*   batch_idx = (const int*)d_in[3];
    float* out = (float*)d_out;

    float* per_step = (float*)d_ws;
    float* flags    = per_step + N_PRED * B;

    fk_kernel<<<N_PRED * B, 256, 0, stream>>>(lp, ps, time_idx, batch_idx,
                                              per_step, flags);
    reduce_kernel<<<1 + N_PRED, 256, 0, stream>>>(per_step, flags, out);
}